// Round 6
// baseline (161.795 us; speedup 1.0000x reference)
//
#include <hip/hip_runtime.h>
#include <math.h>

typedef unsigned short u16;
typedef unsigned int   u32;
typedef __attribute__((ext_vector_type(4))) unsigned short u16x4;
typedef __attribute__((ext_vector_type(8))) unsigned short bf16x8;
typedef __attribute__((ext_vector_type(8))) short sh8;      // MFMA A/B frag (8 bf16)
typedef __attribute__((ext_vector_type(4))) float f32x4;    // MFMA C/D frag

#define BT     4096
#define D      2048
#define NC     8
#define NCOL   144     // 64 selW + 64 upd + 8 mu + 8 zero-pad (9 MFMA col-tiles)
#define KSPLIT 16
#define KR     (D / KSPLIT)   // 128

__device__ __forceinline__ float bf2f(u16 v) {
    u32 u = ((u32)v) << 16;
    float f; __builtin_memcpy(&f, &u, 4); return f;
}
__device__ __forceinline__ u16 f2bf(float f) {
    u32 u; __builtin_memcpy(&u, &f, 4);
    u += 0x7fffu + ((u >> 16) & 1);        // RNE
    return (u16)(u >> 16);
}

// ---- dtype-polymorphic loads: DT=0 bf16 buffers, DT=1 fp32 buffers ----
template<int DT> struct IO;
template<> struct IO<0> {
    static __device__ __forceinline__ float ld1(const void* p, size_t i) {
        return bf2f(((const u16*)p)[i]);
    }
    static __device__ __forceinline__ void ld4(const void* p, size_t i, float* o) {
        u16x4 v = *(const u16x4*)((const u16*)p + i);
#pragma unroll
        for (int k = 0; k < 4; k++) o[k] = bf2f(v[k]);
    }
    static __device__ __forceinline__ void ld8(const void* p, size_t i, float* o) {
        bf16x8 v = *(const bf16x8*)((const u16*)p + i);
#pragma unroll
        for (int k = 0; k < 8; k++) o[k] = bf2f(v[k]);
    }
    static __device__ __forceinline__ void st4(void* p, size_t i, const float* v) {
        u16x4 o;
#pragma unroll
        for (int k = 0; k < 4; k++) o[k] = f2bf(v[k]);
        *(u16x4*)((u16*)p + i) = o;
    }
    static __device__ __forceinline__ u16 ldbf(const void* p, size_t i) {
        return ((const u16*)p)[i];
    }
    static __device__ __forceinline__ sh8 afrag(const void* p, size_t i) {
        return *(const sh8*)((const u16*)p + i);
    }
};
template<> struct IO<1> {
    static __device__ __forceinline__ float ld1(const void* p, size_t i) {
        return ((const float*)p)[i];
    }
    static __device__ __forceinline__ void ld4(const void* p, size_t i, float* o) {
        f32x4 a = *(const f32x4*)((const float*)p + i);
#pragma unroll
        for (int k = 0; k < 4; k++) o[k] = a[k];
    }
    static __device__ __forceinline__ void ld8(const void* p, size_t i, float* o) {
        f32x4 a = *(const f32x4*)((const float*)p + i);
        f32x4 b = *(const f32x4*)((const float*)p + i + 4);
#pragma unroll
        for (int k = 0; k < 4; k++) { o[k] = a[k]; o[4 + k] = b[k]; }
    }
    static __device__ __forceinline__ void st4(void* p, size_t i, const float* v) {
        f32x4 a;
#pragma unroll
        for (int k = 0; k < 4; k++) a[k] = v[k];
        *(f32x4*)((float*)p + i) = a;
    }
    static __device__ __forceinline__ u16 ldbf(const void* p, size_t i) {
        return f2bf(((const float*)p)[i]);
    }
    static __device__ __forceinline__ sh8 afrag(const void* p, size_t i) {
        f32x4 a = *(const f32x4*)((const float*)p + i);
        f32x4 b = *(const f32x4*)((const float*)p + i + 4);
        sh8 r;
#pragma unroll
        for (int k = 0; k < 4; k++) {
            r[k]     = (short)f2bf(a[k]);
            r[4 + k] = (short)f2bf(b[k]);
        }
        return r;
    }
};

// ---------------------------------------------------------------------------
// k_init: blocks 0..575 zero P (2.25 MB), 576..579 zero sumx2 (16 KB),
// block 580 zeroes consts136 + runs the dtype detector (validated R2/R3 A/B:
// fp32 bit-patterns read as bf16 give huge/NaN w.p. ~1; flag=1 -> fp32).
// ---------------------------------------------------------------------------
__global__ __launch_bounds__(256) void k_init(const u16* __restrict__ x,
                                              float* __restrict__ P,
                                              float* __restrict__ sumx2,
                                              float* __restrict__ consts136,
                                              int* __restrict__ flag) {
    int b = blockIdx.x, t = threadIdx.x;
    const f32x4 z4 = {0.f, 0.f, 0.f, 0.f};
    if (b < 576) {
        ((f32x4*)P)[b * 256 + t] = z4;
    } else if (b < 580) {
        ((f32x4*)sumx2)[(b - 576) * 256 + t] = z4;
    } else {
        __shared__ int s;
        if (t == 0) s = 0;
        if (t < 136) consts136[t] = 0.f;
        __syncthreads();
        bool bad = false;
        for (int i = t; i < 1024; i += 256) {
            float v = bf2f(x[i]);
            if (!(fabsf(v) < 1e4f)) bad = true;   // catches NaN too
        }
        if (bad) s = 1;
        __syncthreads();
        if (t == 0) *flag = s;
    }
}

// ---------------------------------------------------------------------------
// k_prep_consts:
//  blocks 0..143 : WtT bf16 [144][2048] (B^T): rows 0..63 selW[n][:,s],
//                  64..127 upd[n][:,h], 128..135 mu[n], 136..143 zeros
//  blocks 144..207: per-concept consts (off/mu2/ub) via block-reduce+atomics
//  blocks 208..271: DGN -> bf16 repack (only when use_dgnb)
// ---------------------------------------------------------------------------
template<int DT>
__device__ __forceinline__ void prep_part(const void* selW, const void* upd,
                                          const void* mu, u16* __restrict__ WtT) {
    int idx = blockIdx.x * 256 + threadIdx.x;
    int j = idx >> 8, d0 = (idx & 255) * 8;
    bf16x8 v;
    if (j < 64) {
        int n = j >> 3, s = j & 7;
#pragma unroll
        for (int i = 0; i < 8; i++) v[i] = IO<DT>::ldbf(selW, ((size_t)n * D + d0 + i) * 8 + s);
    } else if (j < 128) {
        int n = (j - 64) >> 3, h = j & 7;
#pragma unroll
        for (int i = 0; i < 8; i++) v[i] = IO<DT>::ldbf(upd, ((size_t)n * D + d0 + i) * 8 + h);
    } else if (j < 136) {
#pragma unroll
        for (int i = 0; i < 8; i++) v[i] = IO<DT>::ldbf(mu, (size_t)(j - 128) * D + d0 + i);
    } else {
#pragma unroll
        for (int i = 0; i < 8; i++) v[i] = 0;
    }
    *(bf16x8*)(WtT + (size_t)j * D + d0) = v;
}

template<int DT>
__device__ __forceinline__ void consts_part(const void* W, const void* mu,
                                            const void* upd, const void* deb,
                                            float* gOff, float* gMu2, float* gUb) {
    int bid = blockIdx.x - 144;
    int n = bid >> 3, t = threadIdx.x;
    int d = (bid & 7) * 256 + t;

    float mud = IO<DT>::ld1(mu,  (size_t)n * D + d);
    float dbd = IO<DT>::ld1(deb, (size_t)n * D + d);
    float m2 = mud * mud;
    float wv[8], uv[8], o[8], u[8];
    IO<DT>::ld8(W,   ((size_t)n * D + d) * 8, wv);
    IO<DT>::ld8(upd, ((size_t)n * D + d) * 8, uv);
#pragma unroll
    for (int s = 0; s < 8; s++) { o[s] = wv[s] * mud; u[s] = uv[s] * dbd; }

#pragma unroll
    for (int i = 1; i < 64; i <<= 1) {
        m2 += __shfl_xor(m2, i, 64);
#pragma unroll
        for (int s = 0; s < 8; s++) {
            o[s] += __shfl_xor(o[s], i, 64);
            u[s] += __shfl_xor(u[s], i, 64);
        }
    }
    __shared__ float red[4][17];
    int wave = t >> 6, lane = t & 63;
    if (lane == 0) {
        red[wave][0] = m2;
#pragma unroll
        for (int s = 0; s < 8; s++) { red[wave][1 + s] = o[s]; red[wave][9 + s] = u[s]; }
    }
    __syncthreads();
    if (t < 17) {
        float acc = red[0][t] + red[1][t] + red[2][t] + red[3][t];
        if (t == 0)      atomicAdd(&gMu2[n], acc);
        else if (t < 9)  atomicAdd(&gOff[n * 8 + t - 1], acc);
        else             atomicAdd(&gUb[n * 8 + t - 9], acc);
    }
}

template<int DT>
__device__ __forceinline__ void dgnb_part(const void* dgn, u16* __restrict__ dgnb) {
    int idx = (blockIdx.x - 208) * 256 + threadIdx.x;   // 16384 threads x 8 elems
    float v[8];
    IO<DT>::ld8(dgn, (size_t)idx * 8, v);
    bf16x8 o;
#pragma unroll
    for (int k = 0; k < 8; k++) o[k] = f2bf(v[k]);
    *(bf16x8*)(dgnb + (size_t)idx * 8) = o;
}

__global__ __launch_bounds__(256) void k_prep_consts(
    const void* selW, const void* upd, const void* mu, const void* deb,
    const void* dgn, u16* WtT, float* gOff, float* gMu2, float* gUb,
    u16* dgnb, int use_dgnb, const int* flag) {
    int f = *flag;
    if (blockIdx.x < 144) {
        if (f) prep_part<1>(selW, upd, mu, WtT); else prep_part<0>(selW, upd, mu, WtT);
    } else if (blockIdx.x < 208) {
        if (f) consts_part<1>(selW, mu, upd, deb, gOff, gMu2, gUb);
        else   consts_part<0>(selW, mu, upd, deb, gOff, gMu2, gUb);
    } else if (use_dgnb) {
        if (f) dgnb_part<1>(dgn, dgnb); else dgnb_part<0>(dgn, dgnb);
    }
}

// ---------------------------------------------------------------------------
// k_gemm: P[tok][144] += X * WtT^T (bf16 MFMA 16x16x32), Σx² folded in.
// Grid (64,16): 4 waves/block, wave = 16 tokens x K-128. 4096 waves total
// = 4 waves/SIMD (vs R5's 1/SIMD — the occupancy fix). Single P, atomicAdd.
// A-frag: lane l holds X[tok0 + (l&15)][k0 + (l>>4)*8 ..+8] (fp32->bf16 cvt)
// C/D: row(token) = (l>>4)*4 + reg, col = l&15 [m89/m91 verified]
// ---------------------------------------------------------------------------
template<int DT>
__device__ __forceinline__ void gemm_body(const void* X, const u16* __restrict__ WtT,
                                          float* __restrict__ P,
                                          float* __restrict__ sumx2) {
    const int t = threadIdx.x;
    const int w = t >> 6, l = t & 63;
    const int m = l & 15, q = l >> 4;
    const int tok0 = blockIdx.x * 64 + w * 16;
    const int k0 = blockIdx.y * KR;

    const size_t aoff = (size_t)(tok0 + m) * D + k0 + q * 8;
    const u16* bp = WtT + (size_t)m * D + k0 + q * 8;

    f32x4 acc[9];
#pragma unroll
    for (int ct = 0; ct < 9; ct++) acc[ct] = (f32x4){0.f, 0.f, 0.f, 0.f};
    float s2 = 0.f;

#pragma unroll
    for (int ks = 0; ks < KR / 32; ks++) {
        sh8 a = IO<DT>::afrag(X, aoff + ks * 32);
        sh8 b[9];
#pragma unroll
        for (int ct = 0; ct < 9; ct++)
            b[ct] = *(const sh8*)(bp + (size_t)ct * 16 * D + ks * 32);
#pragma unroll
        for (int i = 0; i < 8; i++) {
            float xv = bf2f((u16)a[i]);
            s2 = fmaf(xv, xv, s2);
        }
#pragma unroll
        for (int ct = 0; ct < 9; ct++)
            acc[ct] = __builtin_amdgcn_mfma_f32_16x16x32_bf16(a, b[ct], acc[ct], 0, 0, 0);
    }

    // Σx²: reduce over q (lanes m, m+16, m+32, m+48) then one atomic per token
    s2 += __shfl_xor(s2, 16, 64);
    s2 += __shfl_xor(s2, 32, 64);
    if (l < 16) atomicAdd(&sumx2[tok0 + l], s2);

#pragma unroll
    for (int ct = 0; ct < 9; ct++)
#pragma unroll
        for (int r = 0; r < 4; r++)
            atomicAdd(&P[(size_t)(tok0 + q * 4 + r) * NCOL + ct * 16 + m], acc[ct][r]);
}
__global__ __launch_bounds__(256) void k_gemm(const void* X, const u16* WtT,
                                              float* P, float* sumx2, const int* flag) {
    if (*flag) gemm_body<1>(X, WtT, P, sumx2); else gemm_body<0>(X, WtT, P, sumx2);
}

// ---------------------------------------------------------------------------
// k_gate: thread = (token, concept) pair; 32768 threads. Butterfly argmax in
// lane-groups of 8 (first-max tie-break == np.argmax). Writes sval/c/mx.
// ---------------------------------------------------------------------------
template<int DT>
__device__ __forceinline__ void gate_body(
    const float* __restrict__ P, const float* __restrict__ sumx2,
    const void* CENTER, const void* SLOPE,
    const float* __restrict__ OFF, const float* __restrict__ MU2,
    const float* __restrict__ UB,
    float* __restrict__ svals, int* __restrict__ cs, float* __restrict__ mxs) {
    const int g = blockIdx.x * 256 + threadIdx.x;
    const int tok = g >> 3, n = g & 7;

    const float* pr = P + (size_t)tok * NCOL;
    f32x4 pa = *(const f32x4*)(pr + 8 * n);
    f32x4 pb = *(const f32x4*)(pr + 8 * n + 4);
    float mdot = pr[128 + n];
    float s2 = sumx2[tok];

    float norm2 = s2 - 2.f * mdot + MU2[n];
    float sc = 0.f;
#pragma unroll
    for (int s = 0; s < 4; s++) {
        float d0 = pa[s] - OFF[8 * n + s];
        float d1 = pb[s] - OFF[8 * n + 4 + s];
        sc += d0 * d0 + d1 * d1;
    }
    sc /= norm2;
    float zv = IO<DT>::ld1(SLOPE, n) * (sc - IO<DT>::ld1(CENTER, n));
    int iv = n;
#pragma unroll
    for (int i = 1; i < 8; i <<= 1) {
        float z2 = __shfl_xor(zv, i, 64);
        int   i2 = __shfl_xor(iv, i, 64);
        if (z2 > zv || (z2 == zv && i2 < iv)) { zv = z2; iv = i2; }
    }
    const int c = iv;
    // mx[h]: this lane handles h = n for the winning concept
    float mxv = pr[64 + 8 * c + n] - UB[c * 8 + n];
    mxs[(size_t)tok * 8 + n] = mxv;
    if (n == 0) { svals[tok] = 1.f / (1.f + expf(-zv)); cs[tok] = c; }
}
__global__ __launch_bounds__(256) void k_gate(
    const float* P, const float* sumx2, const void* CENTER, const void* SLOPE,
    const float* OFF, const float* MU2, const float* UB,
    float* svals, int* cs, float* mxs, const int* flag) {
    if (*flag) gate_body<1>(P, sumx2, CENTER, SLOPE, OFF, MU2, UB, svals, cs, mxs);
    else       gate_body<0>(P, sumx2, CENTER, SLOPE, OFF, MU2, UB, svals, cs, mxs);
}

// ---------------------------------------------------------------------------
// k_blend: pure stream. 8192 blocks x 256 threads, thread = 4 d's of a token.
// Fully-coalesced X/OUT/BIAS/DGN(bf16) accesses; gate params from L1.
// ---------------------------------------------------------------------------
template<int DT>
__device__ __forceinline__ void blend_body(
    const void* X, const float* __restrict__ svals, const int* __restrict__ cs,
    const float* __restrict__ mxs, const u16* __restrict__ DGNB,
    const void* DGN, const void* BIAS, void* OUT, int use_dgnb) {
    const int tok = blockIdx.x >> 1;
    const int d0 = (blockIdx.x & 1) * 1024 + threadIdx.x * 4;

    const int c = cs[tok];
    const float sval = svals[tok];
    f32x4 mxa = *(const f32x4*)(mxs + (size_t)tok * 8);
    f32x4 mxb = *(const f32x4*)(mxs + (size_t)tok * 8 + 4);

    float xf[4], bv[4], ov[4];
    IO<DT>::ld4(X,    (size_t)tok * D + d0, xf);
    IO<DT>::ld4(BIAS, (size_t)c * D + d0, bv);
#pragma unroll
    for (int i = 0; i < 4; i++) {
        float dv[8];
        if (use_dgnb) {
            bf16x8 v = *(const bf16x8*)(DGNB + ((size_t)c * D + d0 + i) * 8);
#pragma unroll
            for (int k = 0; k < 8; k++) dv[k] = bf2f(v[k]);
        } else {
            IO<DT>::ld8(DGN, ((size_t)c * D + d0 + i) * 8, dv);
        }
        float du = dv[0] * mxa[0] + dv[1] * mxa[1] + dv[2] * mxa[2] + dv[3] * mxa[3]
                 + dv[4] * mxb[0] + dv[5] * mxb[1] + dv[6] * mxb[2] + dv[7] * mxb[3];
        ov[i] = (1.f - sval) * xf[i] + sval * (bv[i] + du);   // ETA = 1.0
    }
    IO<DT>::st4(OUT, (size_t)tok * D + d0, ov);
}
__global__ __launch_bounds__(256) void k_blend(
    const void* X, const float* svals, const int* cs, const float* mxs,
    const u16* DGNB, const void* DGN, const void* BIAS, void* OUT,
    int use_dgnb, const int* flag) {
    if (*flag) blend_body<1>(X, svals, cs, mxs, DGNB, DGN, BIAS, OUT, use_dgnb);
    else       blend_body<0>(X, svals, cs, mxs, DGNB, DGN, BIAS, OUT, use_dgnb);
}

// ---------------------------------------------------------------------------
extern "C" void kernel_launch(void* const* d_in, const int* in_sizes, int n_in,
                              void* d_out, int out_size, void* d_ws, size_t ws_size,
                              hipStream_t stream) {
    const void* x      = d_in[0];
    const void* selW   = d_in[1];
    const void* mu     = d_in[2];
    const void* center = d_in[3];
    const void* slope  = d_in[4];
    const void* upd    = d_in[5];
    const void* dgn    = d_in[6];
    const void* biasW  = d_in[7];
    const void* debW   = d_in[8];

    // ws layout (16B-aligned)
    char* ws = (char*)d_ws;
    float* P      = (float*)ws;                           // 2,359,296
    float* sumx2  = (float*)(ws + 2359296);               //    16,384
    float* svals  = (float*)(ws + 2375680);               //    16,384
    int*   cs     = (int*)  (ws + 2392064);               //    16,384
    float* mxs    = (float*)(ws + 2408448);               //   131,072
    u16*   WtT    = (u16*)  (ws + 2539520);               //   589,824
    float* consts = (float*)(ws + 3129344);               //       576
    int*   flag   = (int*)  (ws + 3129920);               //        64
    u16*   dgnb   = (u16*)  (ws + 3129984);               //   262,144 (optional)
    float* off = consts, *mu2 = consts + 64, *ub = consts + 72;
    const int use_dgnb = (ws_size >= 3129984 + 262144) ? 1 : 0;

    k_init<<<581, 256, 0, stream>>>((const u16*)x, P, sumx2, consts, flag);
    k_prep_consts<<<272, 256, 0, stream>>>(selW, upd, mu, debW, dgn,
                                           WtT, off, mu2, ub, dgnb, use_dgnb, flag);
    k_gemm <<<dim3(BT / 64, KSPLIT), 256, 0, stream>>>(x, WtT, P, sumx2, flag);
    k_gate <<<BT * NC / 256, 256, 0, stream>>>(P, sumx2, center, slope,
                                               off, mu2, ub, svals, cs, mxs, flag);
    k_blend<<<BT * 2, 256, 0, stream>>>(x, svals, cs, mxs, dgnb, dgn, biasW,
                                        d_out, use_dgnb, flag);
}

// Round 7
// 143.368 us; speedup vs baseline: 1.1285x; 1.1285x over previous
//
#include <hip/hip_runtime.h>
#include <math.h>

typedef unsigned short u16;
typedef unsigned int   u32;
typedef unsigned long long u64;
typedef __attribute__((ext_vector_type(4))) unsigned short u16x4;
typedef __attribute__((ext_vector_type(8))) unsigned short bf16x8;
typedef __attribute__((ext_vector_type(8))) short sh8;      // MFMA A/B frag (8 bf16)
typedef __attribute__((ext_vector_type(4))) float f32x4;    // MFMA C/D frag

#define BT     4096
#define D      2048
#define NC     8
#define NCOL   144     // 64 selW + 64 upd + 8 mu + 8 zero-pad (9 MFMA col-tiles)
#define KSPLIT 8
#define KR     (D / KSPLIT)   // 256

__device__ __forceinline__ float bf2f(u16 v) {
    u32 u = ((u32)v) << 16;
    float f; __builtin_memcpy(&f, &u, 4); return f;
}
__device__ __forceinline__ u16 f2bf(float f) {
    u32 u; __builtin_memcpy(&u, &f, 4);
    u += 0x7fffu + ((u >> 16) & 1);        // RNE
    return (u16)(u >> 16);
}

// ---------------------------------------------------------------------------
// Inline dtype detector (validated R2/R3/R6 A/B): fp32 bit-patterns read as
// bf16 give |v|>1e4 or NaN w.p. ~1 (low halves have uniform-ish exponents);
// genuine bf16 N(0,1) stays |v|<6. All waves check the SAME 256 elements ->
// identical ballot -> block-uniform flag with no barrier, no cross-kernel
// handoff. P(false negative) ~ 0.55^128 ~ 1e-33.
// ---------------------------------------------------------------------------
__device__ __forceinline__ int detect_fp32(const void* xv) {
    const u16* p = (const u16*)xv;
    int l = threadIdx.x & 63;
    bool bad = false;
#pragma unroll
    for (int i = 0; i < 4; i++) {
        float v = bf2f(p[l * 4 + i]);
        if (!(fabsf(v) < 1e4f)) bad = true;   // catches NaN too
    }
    return __ballot(bad) != 0ull;
}

// ---- dtype-polymorphic loads: DT=0 bf16 buffers, DT=1 fp32 buffers ----
template<int DT> struct IO;
template<> struct IO<0> {
    static __device__ __forceinline__ float ld1(const void* p, size_t i) {
        return bf2f(((const u16*)p)[i]);
    }
    static __device__ __forceinline__ void ld4(const void* p, size_t i, float* o) {
        u16x4 v = *(const u16x4*)((const u16*)p + i);
#pragma unroll
        for (int k = 0; k < 4; k++) o[k] = bf2f(v[k]);
    }
    static __device__ __forceinline__ void ld8(const void* p, size_t i, float* o) {
        bf16x8 v = *(const bf16x8*)((const u16*)p + i);
#pragma unroll
        for (int k = 0; k < 8; k++) o[k] = bf2f(v[k]);
    }
    static __device__ __forceinline__ void st4(void* p, size_t i, const float* v) {
        u16x4 o;
#pragma unroll
        for (int k = 0; k < 4; k++) o[k] = f2bf(v[k]);
        *(u16x4*)((u16*)p + i) = o;
    }
    static __device__ __forceinline__ u16 ldbf(const void* p, size_t i) {
        return ((const u16*)p)[i];
    }
    static __device__ __forceinline__ sh8 afrag(const void* p, size_t i) {
        return *(const sh8*)((const u16*)p + i);
    }
};
template<> struct IO<1> {
    static __device__ __forceinline__ float ld1(const void* p, size_t i) {
        return ((const float*)p)[i];
    }
    static __device__ __forceinline__ void ld4(const void* p, size_t i, float* o) {
        f32x4 a = *(const f32x4*)((const float*)p + i);
#pragma unroll
        for (int k = 0; k < 4; k++) o[k] = a[k];
    }
    static __device__ __forceinline__ void ld8(const void* p, size_t i, float* o) {
        f32x4 a = *(const f32x4*)((const float*)p + i);
        f32x4 b = *(const f32x4*)((const float*)p + i + 4);
#pragma unroll
        for (int k = 0; k < 4; k++) { o[k] = a[k]; o[4 + k] = b[k]; }
    }
    static __device__ __forceinline__ void st4(void* p, size_t i, const float* v) {
        f32x4 a;
#pragma unroll
        for (int k = 0; k < 4; k++) a[k] = v[k];
        *(f32x4*)((float*)p + i) = a;
    }
    static __device__ __forceinline__ u16 ldbf(const void* p, size_t i) {
        return f2bf(((const float*)p)[i]);
    }
    static __device__ __forceinline__ sh8 afrag(const void* p, size_t i) {
        f32x4 a = *(const f32x4*)((const float*)p + i);
        f32x4 b = *(const f32x4*)((const float*)p + i + 4);
        sh8 r;
#pragma unroll
        for (int k = 0; k < 4; k++) {
            r[k]     = (short)f2bf(a[k]);
            r[4 + k] = (short)f2bf(b[k]);
        }
        return r;
    }
};

// ---------------------------------------------------------------------------
// k_prep (272 blocks):
//  0..143 : WtT bf16 [144][2048] (B^T): rows 0..63 selW[n][:,s],
//           64..127 upd[n][:,h], 128..135 mu[n], 136..143 zeros
//  144..207: per-concept consts off/mu2/ub (block-reduce + atomics into the
//            pre-memset 576B const table — 1088 atomics total, negligible)
//  208..271: DGN -> bf16 repack (halves blend's L2 traffic)
// ---------------------------------------------------------------------------
template<int DT>
__device__ __forceinline__ void prep_part(const void* selW, const void* upd,
                                          const void* mu, u16* __restrict__ WtT) {
    int idx = blockIdx.x * 256 + threadIdx.x;
    int j = idx >> 8, d0 = (idx & 255) * 8;
    bf16x8 v;
    if (j < 64) {
        int n = j >> 3, s = j & 7;
#pragma unroll
        for (int i = 0; i < 8; i++) v[i] = IO<DT>::ldbf(selW, ((size_t)n * D + d0 + i) * 8 + s);
    } else if (j < 128) {
        int n = (j - 64) >> 3, h = j & 7;
#pragma unroll
        for (int i = 0; i < 8; i++) v[i] = IO<DT>::ldbf(upd, ((size_t)n * D + d0 + i) * 8 + h);
    } else if (j < 136) {
#pragma unroll
        for (int i = 0; i < 8; i++) v[i] = IO<DT>::ldbf(mu, (size_t)(j - 128) * D + d0 + i);
    } else {
#pragma unroll
        for (int i = 0; i < 8; i++) v[i] = 0;
    }
    *(bf16x8*)(WtT + (size_t)j * D + d0) = v;
}

template<int DT>
__device__ __forceinline__ void consts_part(const void* W, const void* mu,
                                            const void* upd, const void* deb,
                                            float* gOff, float* gMu2, float* gUb) {
    int bid = blockIdx.x - 144;
    int n = bid >> 3, t = threadIdx.x;
    int d = (bid & 7) * 256 + t;

    float mud = IO<DT>::ld1(mu,  (size_t)n * D + d);
    float dbd = IO<DT>::ld1(deb, (size_t)n * D + d);
    float m2 = mud * mud;
    float wv[8], uv[8], o[8], u[8];
    IO<DT>::ld8(W,   ((size_t)n * D + d) * 8, wv);
    IO<DT>::ld8(upd, ((size_t)n * D + d) * 8, uv);
#pragma unroll
    for (int s = 0; s < 8; s++) { o[s] = wv[s] * mud; u[s] = uv[s] * dbd; }

#pragma unroll
    for (int i = 1; i < 64; i <<= 1) {
        m2 += __shfl_xor(m2, i, 64);
#pragma unroll
        for (int s = 0; s < 8; s++) {
            o[s] += __shfl_xor(o[s], i, 64);
            u[s] += __shfl_xor(u[s], i, 64);
        }
    }
    __shared__ float red[4][17];
    int wave = t >> 6, lane = t & 63;
    if (lane == 0) {
        red[wave][0] = m2;
#pragma unroll
        for (int s = 0; s < 8; s++) { red[wave][1 + s] = o[s]; red[wave][9 + s] = u[s]; }
    }
    __syncthreads();
    if (t < 17) {
        float acc = red[0][t] + red[1][t] + red[2][t] + red[3][t];
        if (t == 0)      atomicAdd(&gMu2[n], acc);
        else if (t < 9)  atomicAdd(&gOff[n * 8 + t - 1], acc);
        else             atomicAdd(&gUb[n * 8 + t - 9], acc);
    }
}

template<int DT>
__device__ __forceinline__ void dgnb_part(const void* dgn, u16* __restrict__ dgnb) {
    int idx = (blockIdx.x - 208) * 256 + threadIdx.x;   // 16384 threads x 8 elems
    float v[8];
    IO<DT>::ld8(dgn, (size_t)idx * 8, v);
    bf16x8 o;
#pragma unroll
    for (int k = 0; k < 8; k++) o[k] = f2bf(v[k]);
    *(bf16x8*)(dgnb + (size_t)idx * 8) = o;
}

__global__ __launch_bounds__(256) void k_prep(
    const void* x, const void* selW, const void* upd, const void* mu,
    const void* deb, const void* dgn, u16* WtT,
    float* gOff, float* gMu2, float* gUb, u16* dgnb) {
    int f = detect_fp32(x);
    if (blockIdx.x < 144) {
        if (f) prep_part<1>(selW, upd, mu, WtT); else prep_part<0>(selW, upd, mu, WtT);
    } else if (blockIdx.x < 208) {
        if (f) consts_part<1>(selW, mu, upd, deb, gOff, gMu2, gUb);
        else   consts_part<0>(selW, mu, upd, deb, gOff, gMu2, gUb);
    } else {
        if (f) dgnb_part<1>(dgn, dgnb); else dgnb_part<0>(dgn, dgnb);
    }
}

// ---------------------------------------------------------------------------
// k_gemm: Pslice[p][tok][144] = X[:, p*256:(p+1)*256] * WtT^T (bf16 MFMA
// 16x16x32), Σx² per-slice. Grid (64,8) = 512 blocks, 4 waves each
// (8 waves/CU). Wave = 16 tokens x 144 cols x K-256. PLAIN stores only —
// R6's 9.4M atomicAdds (= the 52 µs WRITE_SIZE smoking gun) are gone.
// Slices live in d_out (32 MB, overwritten later by k_blend).
// A-frag: lane l holds X[tok0+(l&15)][k0+(l>>4)*8..+8] (fp32->bf16 in-reg)
// C/D: row(token) = (l>>4)*4 + reg, col = l&15 [m89/m91 verified]
// ---------------------------------------------------------------------------
template<int DT>
__device__ __forceinline__ void gemm_body(const void* X, const u16* __restrict__ WtT,
                                          float* __restrict__ Pslices,
                                          float* __restrict__ sumx2p) {
    const int t = threadIdx.x;
    const int w = t >> 6, l = t & 63;
    const int m = l & 15, q = l >> 4;
    const int tok0 = blockIdx.x * 64 + w * 16;
    const int p = blockIdx.y;
    const int k0 = p * KR;

    const size_t aoff = (size_t)(tok0 + m) * D + k0 + q * 8;
    const u16* bp = WtT + (size_t)m * D + k0 + q * 8;

    f32x4 acc[9];
#pragma unroll
    for (int ct = 0; ct < 9; ct++) acc[ct] = (f32x4){0.f, 0.f, 0.f, 0.f};
    float s2 = 0.f;

#pragma unroll 2
    for (int ks = 0; ks < KR / 32; ks++) {
        sh8 a = IO<DT>::afrag(X, aoff + ks * 32);
        sh8 b[9];
#pragma unroll
        for (int ct = 0; ct < 9; ct++)
            b[ct] = *(const sh8*)(bp + (size_t)ct * 16 * D + ks * 32);
#pragma unroll
        for (int i = 0; i < 8; i++) {
            float xv = bf2f((u16)a[i]);
            s2 = fmaf(xv, xv, s2);
        }
#pragma unroll
        for (int ct = 0; ct < 9; ct++)
            acc[ct] = __builtin_amdgcn_mfma_f32_16x16x32_bf16(a, b[ct], acc[ct], 0, 0, 0);
    }

    // Σx² over this K-slice: reduce lanes {m, m+16, m+32, m+48}, plain store
    s2 += __shfl_xor(s2, 16, 64);
    s2 += __shfl_xor(s2, 32, 64);
    if (l < 16) sumx2p[(size_t)p * BT + tok0 + l] = s2;

    float* Ps = Pslices + (size_t)p * BT * NCOL;
#pragma unroll
    for (int ct = 0; ct < 9; ct++)
#pragma unroll
        for (int r = 0; r < 4; r++)
            Ps[(size_t)(tok0 + q * 4 + r) * NCOL + ct * 16 + m] = acc[ct][r];
}
__global__ __launch_bounds__(256) void k_gemm(const void* X, const u16* WtT,
                                              float* Pslices, float* sumx2p) {
    if (detect_fp32(X)) gemm_body<1>(X, WtT, Pslices, sumx2p);
    else                gemm_body<0>(X, WtT, Pslices, sumx2p);
}

// ---------------------------------------------------------------------------
// k_gate: thread = (token, concept); 32768 threads. Reduces the 8 K-slices
// inline (~45 independent L2 loads/thread, deep pipeline), butterfly argmax
// in lane-groups of 8 (first-max tie-break == np.argmax), writes sval/c/mx.
// ---------------------------------------------------------------------------
template<int DT>
__device__ __forceinline__ void gate_body(
    const float* __restrict__ Pslices, const float* __restrict__ sumx2p,
    const void* CENTER, const void* SLOPE,
    const float* __restrict__ OFF, const float* __restrict__ MU2,
    const float* __restrict__ UB,
    float* __restrict__ svals, int* __restrict__ cs, float* __restrict__ mxs) {
    const int g = blockIdx.x * 256 + threadIdx.x;
    const int tok = g >> 3, n = g & 7;

    f32x4 pa = {0.f, 0.f, 0.f, 0.f}, pb = {0.f, 0.f, 0.f, 0.f};
    float mdot = 0.f, s2 = 0.f;
#pragma unroll
    for (int p = 0; p < KSPLIT; p++) {
        const float* pr = Pslices + ((size_t)p * BT + tok) * NCOL;
        f32x4 a = *(const f32x4*)(pr + 8 * n);
        f32x4 b = *(const f32x4*)(pr + 8 * n + 4);
#pragma unroll
        for (int k = 0; k < 4; k++) { pa[k] += a[k]; pb[k] += b[k]; }
        mdot += pr[128 + n];
        s2 += sumx2p[(size_t)p * BT + tok];
    }

    float norm2 = s2 - 2.f * mdot + MU2[n];
    float sc = 0.f;
#pragma unroll
    for (int s = 0; s < 4; s++) {
        float d0 = pa[s] - OFF[8 * n + s];
        float d1 = pb[s] - OFF[8 * n + 4 + s];
        sc += d0 * d0 + d1 * d1;
    }
    sc /= norm2;
    float zv = IO<DT>::ld1(SLOPE, n) * (sc - IO<DT>::ld1(CENTER, n));
    int iv = n;
#pragma unroll
    for (int i = 1; i < 8; i <<= 1) {
        float z2 = __shfl_xor(zv, i, 64);
        int   i2 = __shfl_xor(iv, i, 64);
        if (z2 > zv || (z2 == zv && i2 < iv)) { zv = z2; iv = i2; }
    }
    const int c = iv;
    // mx[h]: this lane handles h = n for the winning concept (slice-reduced)
    float mxv = 0.f;
#pragma unroll
    for (int p = 0; p < KSPLIT; p++)
        mxv += Pslices[((size_t)p * BT + tok) * NCOL + 64 + 8 * c + n];
    mxs[(size_t)tok * 8 + n] = mxv - UB[c * 8 + n];
    if (n == 0) { svals[tok] = 1.f / (1.f + expf(-zv)); cs[tok] = c; }
}
__global__ __launch_bounds__(256) void k_gate(
    const float* Pslices, const float* sumx2p, const void* X,
    const void* CENTER, const void* SLOPE,
    const float* OFF, const float* MU2, const float* UB,
    float* svals, int* cs, float* mxs) {
    if (detect_fp32(X)) gate_body<1>(Pslices, sumx2p, CENTER, SLOPE, OFF, MU2, UB, svals, cs, mxs);
    else                gate_body<0>(Pslices, sumx2p, CENTER, SLOPE, OFF, MU2, UB, svals, cs, mxs);
}

// ---------------------------------------------------------------------------
// k_blend: pure stream. 8192 blocks x 256 threads, thread = 4 d's of a token.
// Fully-coalesced X/OUT/BIAS + bf16 DGN (half the L2 bytes of fp32).
// Overwrites d_out (slices already consumed by k_gate).
// ---------------------------------------------------------------------------
template<int DT>
__device__ __forceinline__ void blend_body(
    const void* X, const float* __restrict__ svals, const int* __restrict__ cs,
    const float* __restrict__ mxs, const u16* __restrict__ DGNB,
    const void* BIAS, void* OUT) {
    const int tok = blockIdx.x >> 1;
    const int d0 = (blockIdx.x & 1) * 1024 + threadIdx.x * 4;

    const int c = cs[tok];
    const float sval = svals[tok];
    f32x4 mxa = *(const f32x4*)(mxs + (size_t)tok * 8);
    f32x4 mxb = *(const f32x4*)(mxs + (size_t)tok * 8 + 4);

    float xf[4], bv[4], ov[4];
    IO<DT>::ld4(X,    (size_t)tok * D + d0, xf);
    IO<DT>::ld4(BIAS, (size_t)c * D + d0, bv);
#pragma unroll
    for (int i = 0; i < 4; i++) {
        bf16x8 v = *(const bf16x8*)(DGNB + ((size_t)c * D + d0 + i) * 8);
        float du = bf2f(v[0]) * mxa[0] + bf2f(v[1]) * mxa[1]
                 + bf2f(v[2]) * mxa[2] + bf2f(v[3]) * mxa[3]
                 + bf2f(v[4]) * mxb[0] + bf2f(v[5]) * mxb[1]
                 + bf2f(v[6]) * mxb[2] + bf2f(v[7]) * mxb[3];
        ov[i] = (1.f - sval) * xf[i] + sval * (bv[i] + du);   // ETA = 1.0
    }
    IO<DT>::st4(OUT, (size_t)tok * D + d0, ov);
}
__global__ __launch_bounds__(256) void k_blend(
    const void* X, const float* svals, const int* cs, const float* mxs,
    const u16* DGNB, const void* BIAS, void* OUT) {
    if (detect_fp32(X)) blend_body<1>(X, svals, cs, mxs, DGNB, BIAS, OUT);
    else                blend_body<0>(X, svals, cs, mxs, DGNB, BIAS, OUT);
}

// ---------------------------------------------------------------------------
extern "C" void kernel_launch(void* const* d_in, const int* in_sizes, int n_in,
                              void* d_out, int out_size, void* d_ws, size_t ws_size,
                              hipStream_t stream) {
    const void* x      = d_in[0];
    const void* selW   = d_in[1];
    const void* mu     = d_in[2];
    const void* center = d_in[3];
    const void* slope  = d_in[4];
    const void* upd    = d_in[5];
    const void* dgn    = d_in[6];
    const void* biasW  = d_in[7];
    const void* debW   = d_in[8];

    // P slices (8 x 2.36 MB = 18.9 MB) live in d_out (32 MB, rewritten by
    // k_blend last). ws: 1.12 MB total — well under the proven >= 3.13 MB.
    float* Pslices = (float*)d_out;
    char* ws = (char*)d_ws;
    float* sumx2p = (float*)ws;                   // 131072
    float* svals  = (float*)(ws + 131072);        //  16384
    int*   cs     = (int*)  (ws + 147456);        //  16384
    float* mxs    = (float*)(ws + 163840);        // 131072
    u16*   WtT    = (u16*)  (ws + 294912);        // 589824
    u16*   dgnb   = (u16*)  (ws + 884736);        // 262144
    float* consts = (float*)(ws + 1146880);       //    576
    float* off = consts, *mu2 = consts + 64, *ub = consts + 72;

    hipMemsetAsync(consts, 0, 576, stream);       // consts atomics target
    k_prep <<<272, 256, 0, stream>>>(x, selW, upd, mu, debW, dgn,
                                     WtT, off, mu2, ub, dgnb);
    k_gemm <<<dim3(BT / 64, KSPLIT), 256, 0, stream>>>(x, WtT, Pslices, sumx2p);
    k_gate <<<BT * NC / 256, 256, 0, stream>>>(Pslices, sumx2p, x, center, slope,
                                               off, mu2, ub, svals, cs, mxs);
    k_blend<<<BT * 2, 256, 0, stream>>>(x, svals, cs, mxs, dgnb, biasW, d_out);
}